// Round 6
// baseline (45.613 us; speedup 1.0000x reference)
//
#include <hip/hip_runtime.h>
#include <math.h>

// Sizes (fixed by the problem)
#define Bb 8
#define Tt 32
#define Hh 64
#define Ww 64
#define Cc 3
#define Ff 24
#define Uu 128

typedef float v2f __attribute__((ext_vector_type(2)));

// Fast activations: |err| ~1e-6, threshold is 1.86e-4.
__device__ __forceinline__ float fast_sigmoid(float x) {
    float e = __builtin_amdgcn_exp2f(-1.442695040888963f * x);
    return __builtin_amdgcn_rcpf(1.f + e);
}
__device__ __forceinline__ float fast_tanh(float x) {
    float e = __builtin_amdgcn_exp2f(-2.885390081777927f * x);
    return 2.f * __builtin_amdgcn_rcpf(1.f + e) - 1.f;
}

// ---------------------------------------------------------------------------
// Kernel 1: fused per-frame stats + analytic double-conv + global-avg-pool
// + input-part of gate preactivations (gpre fused in; feat never hits HBM).
// feat[24] = mean_{h,w} conv2(conv1(x)) via 25 region stats/channel
// (linear convs + SAME padding collapse under the mean). Then
// G[(t*8+b)*512 + g*128+u] = bias_g[u] + feat @ W_g[0:24, u].
// ---------------------------------------------------------------------------
__global__ void convfeat_kernel(const float* __restrict__ x,
                                const float* __restrict__ w1, const float* __restrict__ b1,
                                const float* __restrict__ w2, const float* __restrict__ b2,
                                const float* __restrict__ Wf, const float* __restrict__ bf,
                                const float* __restrict__ Wi, const float* __restrict__ bi,
                                const float* __restrict__ Wc, const float* __restrict__ bc,
                                const float* __restrict__ Wo, const float* __restrict__ bo,
                                float* __restrict__ G) {
    int n = blockIdx.x;                       // frame = b*T + t
    const float* xf = x + (size_t)n * (Hh * Ww * Cc);
    int tid  = threadIdx.x;                   // 0..255
    int row  = tid >> 2;
    int part = tid & 3;

    __shared__ float partial[256][3];
    __shared__ float rowsum[64][3];
    __shared__ float colv[64][12];
    __shared__ float st[75];                  // [c*25 + j]
    __shared__ float yst[24][9];
    __shared__ float feats[24];

    float s0 = 0.f, s1 = 0.f, s2 = 0.f;
    const float4* p4 = (const float4*)(xf + (row * Ww + part * 16) * Cc);
#pragma unroll
    for (int i = 0; i < 12; ++i) {
        float4 v = p4[i];
        int j = i * 4;
        float vv[4] = {v.x, v.y, v.z, v.w};
#pragma unroll
        for (int l = 0; l < 4; ++l) {
            int c = (j + l) % 3;
            if (c == 0) s0 += vv[l]; else if (c == 1) s1 += vv[l]; else s2 += vv[l];
        }
    }
    partial[tid][0] = s0; partial[tid][1] = s1; partial[tid][2] = s2;

    if (tid < 64) {
        int r = tid;
#pragma unroll
        for (int w4 = 0; w4 < 4; ++w4) {
            int w = (w4 < 2) ? w4 : 60 + w4;
#pragma unroll
            for (int c = 0; c < 3; ++c) colv[r][w4 * 3 + c] = xf[(r * Ww + w) * Cc + c];
        }
    }
    __syncthreads();

    if (part == 0) {
#pragma unroll
        for (int c = 0; c < 3; ++c)
            rowsum[row][c] = partial[tid][c] + partial[tid + 1][c]
                           + partial[tid + 2][c] + partial[tid + 3][c];
    }
    __syncthreads();

    if (tid < 3) {
        float t = 0.f;
        for (int r = 0; r < 64; ++r) t += rowsum[r][tid];
        st[tid * 25 + 0] = t;
    }
    if (tid >= 4 && tid < 16) {
        int k = tid - 4; int ri = k / 3, c = k % 3;
        int r = (ri < 2) ? ri : 60 + ri;
        st[c * 25 + 1 + ri] = rowsum[r][c];
    }
    if (tid >= 64 && tid < 76) {
        int k = tid - 64;
        float t = 0.f;
        for (int r = 0; r < 64; ++r) t += colv[r][k];
        int wi = k / 3, c = k % 3;
        st[c * 25 + 5 + wi] = t;
    }
    if (tid >= 128 && tid < 176) {
        int k = tid - 128; int pos = k / 3, c = k % 3;
        int ri = pos >> 2, wi = pos & 3;
        int r = (ri < 2) ? ri : 60 + ri;
        int w = (wi < 2) ? wi : 60 + wi;
        st[c * 25 + 9 + pos] = xf[(r * Ww + w) * Cc + c];
    }
    __syncthreads();

    if (tid < 24) {
        int f = tid;
        float Sy = 0, r0 = 0, r63 = 0, c0 = 0, c63 = 0, y00 = 0, y0W = 0, yH0 = 0, yHW = 0;
        for (int c = 0; c < 3; ++c) {
            const float* S = st + c * 25;
            float Sx = S[0];
            float rX[4] = {S[1], S[2], S[3], S[4]};
            float cX[4] = {S[5], S[6], S[7], S[8]};
            const float* X = S + 9;
            #define W1(p, q) w1[(((p) * 3 + (q)) * 3 + c) * 24 + f]
#pragma unroll
            for (int p = 0; p < 3; ++p)
#pragma unroll
                for (int q = 0; q < 3; ++q) {
                    float t = Sx;
                    if (p == 0) t -= rX[3];
                    if (p == 2) t -= rX[0];
                    if (q == 0) t -= cX[3];
                    if (q == 2) t -= cX[0];
                    if (p == 0 && q == 0) t += X[3 * 4 + 3];
                    if (p == 0 && q == 2) t += X[3 * 4 + 0];
                    if (p == 2 && q == 0) t += X[0 * 4 + 3];
                    if (p == 2 && q == 2) t += X[0 * 4 + 0];
                    Sy += W1(p, q) * t;
                }
#pragma unroll
            for (int q = 0; q < 3; ++q) {
                float Rr0  = rX[0] - ((q == 0) ? X[0 * 4 + 3] : 0.f) - ((q == 2) ? X[0 * 4 + 0] : 0.f);
                float Rr1  = rX[1] - ((q == 0) ? X[1 * 4 + 3] : 0.f) - ((q == 2) ? X[1 * 4 + 0] : 0.f);
                float Rr62 = rX[2] - ((q == 0) ? X[2 * 4 + 3] : 0.f) - ((q == 2) ? X[2 * 4 + 0] : 0.f);
                float Rr63 = rX[3] - ((q == 0) ? X[3 * 4 + 3] : 0.f) - ((q == 2) ? X[3 * 4 + 0] : 0.f);
                r0  += W1(1, q) * Rr0  + W1(2, q) * Rr1;
                r63 += W1(0, q) * Rr62 + W1(1, q) * Rr63;
            }
#pragma unroll
            for (int p = 0; p < 3; ++p) {
                float Rc0  = cX[0] - ((p == 0) ? X[3 * 4 + 0] : 0.f) - ((p == 2) ? X[0 * 4 + 0] : 0.f);
                float Rc1  = cX[1] - ((p == 0) ? X[3 * 4 + 1] : 0.f) - ((p == 2) ? X[0 * 4 + 1] : 0.f);
                float Rc62 = cX[2] - ((p == 0) ? X[3 * 4 + 2] : 0.f) - ((p == 2) ? X[0 * 4 + 2] : 0.f);
                float Rc63 = cX[3] - ((p == 0) ? X[3 * 4 + 3] : 0.f) - ((p == 2) ? X[0 * 4 + 3] : 0.f);
                c0  += W1(p, 1) * Rc0  + W1(p, 2) * Rc1;
                c63 += W1(p, 0) * Rc62 + W1(p, 1) * Rc63;
            }
            y00 += W1(1, 1) * X[0 * 4 + 0] + W1(1, 2) * X[0 * 4 + 1]
                 + W1(2, 1) * X[1 * 4 + 0] + W1(2, 2) * X[1 * 4 + 1];
            y0W += W1(1, 0) * X[0 * 4 + 2] + W1(1, 1) * X[0 * 4 + 3]
                 + W1(2, 0) * X[1 * 4 + 2] + W1(2, 1) * X[1 * 4 + 3];
            yH0 += W1(0, 1) * X[2 * 4 + 0] + W1(0, 2) * X[2 * 4 + 1]
                 + W1(1, 1) * X[3 * 4 + 0] + W1(1, 2) * X[3 * 4 + 1];
            yHW += W1(0, 0) * X[2 * 4 + 2] + W1(0, 1) * X[2 * 4 + 3]
                 + W1(1, 0) * X[3 * 4 + 2] + W1(1, 1) * X[3 * 4 + 3];
            #undef W1
        }
        float bb = b1[f];
        yst[f][0] = Sy + 4096.f * bb;
        yst[f][1] = r0 + 64.f * bb;
        yst[f][2] = r63 + 64.f * bb;
        yst[f][3] = c0 + 64.f * bb;
        yst[f][4] = c63 + 64.f * bb;
        yst[f][5] = y00 + bb; yst[f][6] = y0W + bb;
        yst[f][7] = yH0 + bb; yst[f][8] = yHW + bb;
    }
    __syncthreads();

    if (tid < 24) {
        int g = tid;
        float acc = 0.f;
        for (int f = 0; f < 24; ++f) {
            float Sy = yst[f][0], rY0 = yst[f][1], rY63 = yst[f][2], cY0 = yst[f][3], cY63 = yst[f][4];
            float yc00 = yst[f][5], yc0W = yst[f][6], ycH0 = yst[f][7], ycHW = yst[f][8];
#pragma unroll
            for (int p = 0; p < 3; ++p)
#pragma unroll
                for (int q = 0; q < 3; ++q) {
                    float t = Sy;
                    if (p == 0) t -= rY63;
                    if (p == 2) t -= rY0;
                    if (q == 0) t -= cY63;
                    if (q == 2) t -= cY0;
                    if (p == 0 && q == 0) t += ycHW;
                    if (p == 0 && q == 2) t += ycH0;
                    if (p == 2 && q == 0) t += yc0W;
                    if (p == 2 && q == 2) t += yc00;
                    acc += w2[(((p * 3 + q) * 24 + f) * 24) + g] * t;
                }
        }
        feats[g] = b2[g] + acc * (1.f / 4096.f);
    }
    __syncthreads();

    // ---- fused gpre: 2 gate-columns per thread (512 cols total) ----
    int b = n >> 5, t = n & 31;               // Tt = 32
    float* Gdst = G + ((size_t)(t * Bb + b)) * 512;
#pragma unroll
    for (int rep = 0; rep < 2; ++rep) {
        int col = tid + rep * 256;
        int gg = col >> 7, u = col & 127;     // wave-uniform gg (64 | 128)
        const float* W    = (gg == 0) ? Wf : (gg == 1) ? Wi : (gg == 2) ? Wc : Wo;
        const float* bias = (gg == 0) ? bf : (gg == 1) ? bi : (gg == 2) ? bc : bo;
        float acc = bias[u];
#pragma unroll
        for (int k = 0; k < Ff; ++k) acc += feats[k] * W[k * Uu + u];
        Gdst[col] = acc;
    }
}

// ---------------------------------------------------------------------------
// Kernel 2: LSTM recurrence. One block per batch element, 1024 threads
// (16 waves -> hard 128-VGPR cap, 4 waves/SIMD).
// Weight residency is FORCED this round: 32 named v2f loads feed volatile
// keep-alive asm in the prologue. A volatile asm executes exactly once and
// cannot be sunk/duplicated into the loop, and its outputs cannot be
// rematerialized -- so the weights stay in VGPRs (est. ~110 < 128 cap).
// Rounds 1-5 all silently lost residency to load sinking / scratch demotion.
// Thread (up = tid&63, g = (tid>>6)&3, q = tid>>8):
//   phase A: acc(v2f) = sum_{r<32} W_g[24+32q+r][2up..2up+1] * h[32q+r]
//            (h via broadcast ds_read_b64 + pk_fma op_sel splat)
//   phase B (tid<128): sum 4 chunk partials/gate + G, activations, c/h update.
// G for step t+1 is prefetched into registers during step t (~1000 cyc cover
// for the cross-XCD read). 2 barriers per step.
// ---------------------------------------------------------------------------
__global__ __launch_bounds__(1024) void lstm_kernel(
        const float* __restrict__ G,
        const float* __restrict__ Wf, const float* __restrict__ Wi,
        const float* __restrict__ Wc, const float* __restrict__ Wo,
        const float* __restrict__ out_w, const float* __restrict__ out_b,
        float* __restrict__ out) {
    int b   = blockIdx.x;
    int tid = threadIdx.x;
    int up  = tid & 63;                       // unit pair
    int g   = (tid >> 6) & 3;                 // gate (wave-uniform)
    int q   = tid >> 8;                       // row chunk (wave-uniform)
    const float* Wg = (g == 0) ? Wf : (g == 1) ? Wi : (g == 2) ? Wc : Wo;

    // 64 VGPRs of recurrent weights as named SSA values.
    const float* wbase = Wg + (size_t)(Ff + 32 * q) * Uu + 2 * up;
#define LDW(i) v2f w##i = *(const v2f*)(wbase + (size_t)(i) * Uu)
    LDW(0);  LDW(1);  LDW(2);  LDW(3);  LDW(4);  LDW(5);  LDW(6);  LDW(7);
    LDW(8);  LDW(9);  LDW(10); LDW(11); LDW(12); LDW(13); LDW(14); LDW(15);
    LDW(16); LDW(17); LDW(18); LDW(19); LDW(20); LDW(21); LDW(22); LDW(23);
    LDW(24); LDW(25); LDW(26); LDW(27); LDW(28); LDW(29); LDW(30); LDW(31);
#undef LDW
    // Volatile keep-alive: forces the loads to complete here, exactly once;
    // the asm outputs are the loop-live values and cannot be rematerialized.
#define KA8(a,b_,c,d,e,f,g_,h) asm volatile("" : "+v"(a),"+v"(b_),"+v"(c),\
        "+v"(d),"+v"(e),"+v"(f),"+v"(g_),"+v"(h))
    KA8(w0,  w1,  w2,  w3,  w4,  w5,  w6,  w7);
    KA8(w8,  w9,  w10, w11, w12, w13, w14, w15);
    KA8(w16, w17, w18, w19, w20, w21, w22, w23);
    KA8(w24, w25, w26, w27, w28, w29, w30, w31);
#undef KA8

    __shared__ float hs[Uu];
    __shared__ float part[16][Uu];            // [q*4+g][u]
    __shared__ float hist[Tt][Uu];

    float cs = 0.f;
    if (tid < Uu) hs[tid] = 0.f;

    // G prefetch registers: gc* = current step, gn* = next step.
    float gc0 = 0.f, gc1 = 0.f, gc2 = 0.f, gc3 = 0.f;
    if (tid < Uu) {
        const float* Gt = G + ((size_t)(0 * Bb + b)) * 512 + tid;
        gc0 = Gt[0]; gc1 = Gt[128]; gc2 = Gt[256]; gc3 = Gt[384];
    }
    __syncthreads();

    for (int t = 0; t < Tt; ++t) {
        // Issue next step's G loads first; consumed in phase B of step t+1.
        float gn0 = 0.f, gn1 = 0.f, gn2 = 0.f, gn3 = 0.f;
        if (tid < Uu && t + 1 < Tt) {
            const float* Gt = G + ((size_t)((t + 1) * Bb + b)) * 512 + tid;
            gn0 = Gt[0]; gn1 = Gt[128]; gn2 = Gt[256]; gn3 = Gt[384];
        }

        // phase A: 16 broadcast ds_read_b64 + 32 pk_fma (2 indep chains).
        v2f ae = {0.f, 0.f}, ao = {0.f, 0.f};
        const v2f* hp = (const v2f*)(hs + q * 32);
        // even row 2j: splat h2.lo (op_sel_hi[1]=0); odd row: splat h2.hi.
#define FMA2(j, we, wo_) { v2f h2 = hp[j]; \
        asm("v_pk_fma_f32 %0, %1, %2, %0 op_sel:[0,0,0] op_sel_hi:[1,0,1]" \
            : "+v"(ae) : "v"(we), "v"(h2)); \
        asm("v_pk_fma_f32 %0, %1, %2, %0 op_sel:[0,1,0] op_sel_hi:[1,1,1]" \
            : "+v"(ao) : "v"(wo_), "v"(h2)); }
        FMA2(0,  w0,  w1);  FMA2(1,  w2,  w3);
        FMA2(2,  w4,  w5);  FMA2(3,  w6,  w7);
        FMA2(4,  w8,  w9);  FMA2(5,  w10, w11);
        FMA2(6,  w12, w13); FMA2(7,  w14, w15);
        FMA2(8,  w16, w17); FMA2(9,  w18, w19);
        FMA2(10, w20, w21); FMA2(11, w22, w23);
        FMA2(12, w24, w25); FMA2(13, w26, w27);
        FMA2(14, w28, w29); FMA2(15, w30, w31);
#undef FMA2
        v2f acc = ae + ao;
        *(v2f*)&part[q * 4 + g][2 * up] = acc;
        __syncthreads();

        // phase B: state update on 128 threads.
        if (tid < Uu) {
            int u = tid;
            float sf = part[0][u] + part[4][u] + part[8][u]  + part[12][u] + gc0;
            float si = part[1][u] + part[5][u] + part[9][u]  + part[13][u] + gc1;
            float sg = part[2][u] + part[6][u] + part[10][u] + part[14][u] + gc2;
            float so = part[3][u] + part[7][u] + part[11][u] + part[15][u] + gc3;
            float f  = fast_sigmoid(sf);
            float i  = fast_sigmoid(si);
            float gg = fast_tanh(sg);
            float o  = fast_sigmoid(so);
            cs = cs * f + i * gg;
            float hn = fast_tanh(cs) * o;
            hs[u] = hn;
            hist[t][u] = hn;
        }
        gc0 = gn0; gc1 = gn1; gc2 = gn2; gc3 = gn3;
        __syncthreads();
    }

    // Epilogue: out[b][t] = hist[t] . out_w + out_b, 32 threads per t.
    int tt = tid >> 5, j = tid & 31;
    const float4* hh = (const float4*)(&hist[tt][j * 4]);
    float4 a0 = hh[0];
    const float* owp = out_w + j * 4;
    float pw = a0.x * owp[0] + a0.y * owp[1] + a0.z * owp[2] + a0.w * owp[3];
#pragma unroll
    for (int off = 16; off > 0; off >>= 1) pw += __shfl_down(pw, off, 32);
    if (j == 0) out[b * Tt + tt] = pw + out_b[0];
}

// ---------------------------------------------------------------------------
extern "C" void kernel_launch(void* const* d_in, const int* in_sizes, int n_in,
                              void* d_out, int out_size, void* d_ws, size_t ws_size,
                              hipStream_t stream) {
    const float* x   = (const float*)d_in[0];
    const float* w1  = (const float*)d_in[1];
    const float* b1  = (const float*)d_in[2];
    const float* w2  = (const float*)d_in[3];
    const float* b2  = (const float*)d_in[4];
    const float* Wf  = (const float*)d_in[5];
    const float* bf  = (const float*)d_in[6];
    const float* Wi  = (const float*)d_in[7];
    const float* bi  = (const float*)d_in[8];
    const float* Wc  = (const float*)d_in[9];
    const float* bc  = (const float*)d_in[10];
    const float* Wo  = (const float*)d_in[11];
    const float* bo  = (const float*)d_in[12];
    const float* ow  = (const float*)d_in[13];
    const float* ob  = (const float*)d_in[14];
    float* out = (float*)d_out;

    float* G = (float*)d_ws;                  // 256*512 = 131072 floats

    convfeat_kernel<<<Bb * Tt, 256, 0, stream>>>(x, w1, b1, w2, b2,
                                                 Wf, bf, Wi, bi, Wc, bc, Wo, bo, G);
    lstm_kernel<<<Bb, 1024, 0, stream>>>(G, Wf, Wi, Wc, Wo, ow, ob, out);
}

// Round 7
// 39.655 us; speedup vs baseline: 1.1502x; 1.1502x over previous
//
#include <hip/hip_runtime.h>
#include <math.h>

// Sizes (fixed by the problem)
#define Bb 8
#define Tt 32
#define Hh 64
#define Ww 64
#define Cc 3
#define Ff 24
#define Uu 128

typedef float v2f __attribute__((ext_vector_type(2)));

// Fast activations: |err| ~1e-6, threshold is 1.86e-4.
__device__ __forceinline__ float fast_sigmoid(float x) {
    float e = __builtin_amdgcn_exp2f(-1.442695040888963f * x);
    return __builtin_amdgcn_rcpf(1.f + e);
}
__device__ __forceinline__ float fast_tanh(float x) {
    float e = __builtin_amdgcn_exp2f(-2.885390081777927f * x);
    return 2.f * __builtin_amdgcn_rcpf(1.f + e) - 1.f;
}

// ---------------------------------------------------------------------------
// Kernel 1: fused per-frame stats + analytic double-conv + global-avg-pool
// + input-part of gate preactivations (feat never hits HBM).
// feat[24] = mean_{h,w} conv2(conv1(x)) via 25 region stats/channel
// (linear convs + SAME padding collapse under the mean). Then
// G[(t*8+b)*512 + g*128+u] = bias_g[u] + feat @ W_g[0:24, u].
// ---------------------------------------------------------------------------
__global__ void convfeat_kernel(const float* __restrict__ x,
                                const float* __restrict__ w1, const float* __restrict__ b1,
                                const float* __restrict__ w2, const float* __restrict__ b2,
                                const float* __restrict__ Wf, const float* __restrict__ bf,
                                const float* __restrict__ Wi, const float* __restrict__ bi,
                                const float* __restrict__ Wc, const float* __restrict__ bc,
                                const float* __restrict__ Wo, const float* __restrict__ bo,
                                float* __restrict__ G) {
    int n = blockIdx.x;                       // frame = b*T + t
    const float* xf = x + (size_t)n * (Hh * Ww * Cc);
    int tid  = threadIdx.x;                   // 0..255
    int row  = tid >> 2;
    int part = tid & 3;

    __shared__ float partial[256][3];
    __shared__ float rowsum[64][3];
    __shared__ float colv[64][12];
    __shared__ float st[75];                  // [c*25 + j]
    __shared__ float yst[24][9];
    __shared__ float feats[24];

    float s0 = 0.f, s1 = 0.f, s2 = 0.f;
    const float4* p4 = (const float4*)(xf + (row * Ww + part * 16) * Cc);
#pragma unroll
    for (int i = 0; i < 12; ++i) {
        float4 v = p4[i];
        int j = i * 4;
        float vv[4] = {v.x, v.y, v.z, v.w};
#pragma unroll
        for (int l = 0; l < 4; ++l) {
            int c = (j + l) % 3;
            if (c == 0) s0 += vv[l]; else if (c == 1) s1 += vv[l]; else s2 += vv[l];
        }
    }
    partial[tid][0] = s0; partial[tid][1] = s1; partial[tid][2] = s2;

    if (tid < 64) {
        int r = tid;
#pragma unroll
        for (int w4 = 0; w4 < 4; ++w4) {
            int w = (w4 < 2) ? w4 : 60 + w4;
#pragma unroll
            for (int c = 0; c < 3; ++c) colv[r][w4 * 3 + c] = xf[(r * Ww + w) * Cc + c];
        }
    }
    __syncthreads();

    if (part == 0) {
#pragma unroll
        for (int c = 0; c < 3; ++c)
            rowsum[row][c] = partial[tid][c] + partial[tid + 1][c]
                           + partial[tid + 2][c] + partial[tid + 3][c];
    }
    __syncthreads();

    if (tid < 3) {
        float t = 0.f;
        for (int r = 0; r < 64; ++r) t += rowsum[r][tid];
        st[tid * 25 + 0] = t;
    }
    if (tid >= 4 && tid < 16) {
        int k = tid - 4; int ri = k / 3, c = k % 3;
        int r = (ri < 2) ? ri : 60 + ri;
        st[c * 25 + 1 + ri] = rowsum[r][c];
    }
    if (tid >= 64 && tid < 76) {
        int k = tid - 64;
        float t = 0.f;
        for (int r = 0; r < 64; ++r) t += colv[r][k];
        int wi = k / 3, c = k % 3;
        st[c * 25 + 5 + wi] = t;
    }
    if (tid >= 128 && tid < 176) {
        int k = tid - 128; int pos = k / 3, c = k % 3;
        int ri = pos >> 2, wi = pos & 3;
        int r = (ri < 2) ? ri : 60 + ri;
        int w = (wi < 2) ? wi : 60 + wi;
        st[c * 25 + 9 + pos] = xf[(r * Ww + w) * Cc + c];
    }
    __syncthreads();

    if (tid < 24) {
        int f = tid;
        float Sy = 0, r0 = 0, r63 = 0, c0 = 0, c63 = 0, y00 = 0, y0W = 0, yH0 = 0, yHW = 0;
        for (int c = 0; c < 3; ++c) {
            const float* S = st + c * 25;
            float Sx = S[0];
            float rX[4] = {S[1], S[2], S[3], S[4]};
            float cX[4] = {S[5], S[6], S[7], S[8]};
            const float* X = S + 9;
            #define W1(p, q) w1[(((p) * 3 + (q)) * 3 + c) * 24 + f]
#pragma unroll
            for (int p = 0; p < 3; ++p)
#pragma unroll
                for (int q = 0; q < 3; ++q) {
                    float t = Sx;
                    if (p == 0) t -= rX[3];
                    if (p == 2) t -= rX[0];
                    if (q == 0) t -= cX[3];
                    if (q == 2) t -= cX[0];
                    if (p == 0 && q == 0) t += X[3 * 4 + 3];
                    if (p == 0 && q == 2) t += X[3 * 4 + 0];
                    if (p == 2 && q == 0) t += X[0 * 4 + 3];
                    if (p == 2 && q == 2) t += X[0 * 4 + 0];
                    Sy += W1(p, q) * t;
                }
#pragma unroll
            for (int q = 0; q < 3; ++q) {
                float Rr0  = rX[0] - ((q == 0) ? X[0 * 4 + 3] : 0.f) - ((q == 2) ? X[0 * 4 + 0] : 0.f);
                float Rr1  = rX[1] - ((q == 0) ? X[1 * 4 + 3] : 0.f) - ((q == 2) ? X[1 * 4 + 0] : 0.f);
                float Rr62 = rX[2] - ((q == 0) ? X[2 * 4 + 3] : 0.f) - ((q == 2) ? X[2 * 4 + 0] : 0.f);
                float Rr63 = rX[3] - ((q == 0) ? X[3 * 4 + 3] : 0.f) - ((q == 2) ? X[3 * 4 + 0] : 0.f);
                r0  += W1(1, q) * Rr0  + W1(2, q) * Rr1;
                r63 += W1(0, q) * Rr62 + W1(1, q) * Rr63;
            }
#pragma unroll
            for (int p = 0; p < 3; ++p) {
                float Rc0  = cX[0] - ((p == 0) ? X[3 * 4 + 0] : 0.f) - ((p == 2) ? X[0 * 4 + 0] : 0.f);
                float Rc1  = cX[1] - ((p == 0) ? X[3 * 4 + 1] : 0.f) - ((p == 2) ? X[0 * 4 + 1] : 0.f);
                float Rc62 = cX[2] - ((p == 0) ? X[3 * 4 + 2] : 0.f) - ((p == 2) ? X[0 * 4 + 2] : 0.f);
                float Rc63 = cX[3] - ((p == 0) ? X[3 * 4 + 3] : 0.f) - ((p == 2) ? X[0 * 4 + 3] : 0.f);
                c0  += W1(p, 1) * Rc0  + W1(p, 2) * Rc1;
                c63 += W1(p, 0) * Rc62 + W1(p, 1) * Rc63;
            }
            y00 += W1(1, 1) * X[0 * 4 + 0] + W1(1, 2) * X[0 * 4 + 1]
                 + W1(2, 1) * X[1 * 4 + 0] + W1(2, 2) * X[1 * 4 + 1];
            y0W += W1(1, 0) * X[0 * 4 + 2] + W1(1, 1) * X[0 * 4 + 3]
                 + W1(2, 0) * X[1 * 4 + 2] + W1(2, 1) * X[1 * 4 + 3];
            yH0 += W1(0, 1) * X[2 * 4 + 0] + W1(0, 2) * X[2 * 4 + 1]
                 + W1(1, 1) * X[3 * 4 + 0] + W1(1, 2) * X[3 * 4 + 1];
            yHW += W1(0, 0) * X[2 * 4 + 2] + W1(0, 1) * X[2 * 4 + 3]
                 + W1(1, 0) * X[3 * 4 + 2] + W1(1, 1) * X[3 * 4 + 3];
            #undef W1
        }
        float bb = b1[f];
        yst[f][0] = Sy + 4096.f * bb;
        yst[f][1] = r0 + 64.f * bb;
        yst[f][2] = r63 + 64.f * bb;
        yst[f][3] = c0 + 64.f * bb;
        yst[f][4] = c63 + 64.f * bb;
        yst[f][5] = y00 + bb; yst[f][6] = y0W + bb;
        yst[f][7] = yH0 + bb; yst[f][8] = yHW + bb;
    }
    __syncthreads();

    if (tid < 24) {
        int g = tid;
        float acc = 0.f;
        for (int f = 0; f < 24; ++f) {
            float Sy = yst[f][0], rY0 = yst[f][1], rY63 = yst[f][2], cY0 = yst[f][3], cY63 = yst[f][4];
            float yc00 = yst[f][5], yc0W = yst[f][6], ycH0 = yst[f][7], ycHW = yst[f][8];
#pragma unroll
            for (int p = 0; p < 3; ++p)
#pragma unroll
                for (int q = 0; q < 3; ++q) {
                    float t = Sy;
                    if (p == 0) t -= rY63;
                    if (p == 2) t -= rY0;
                    if (q == 0) t -= cY63;
                    if (q == 2) t -= cY0;
                    if (p == 0 && q == 0) t += ycHW;
                    if (p == 0 && q == 2) t += ycH0;
                    if (p == 2 && q == 0) t += yc0W;
                    if (p == 2 && q == 2) t += yc00;
                    acc += w2[(((p * 3 + q) * 24 + f) * 24) + g] * t;
                }
        }
        feats[g] = b2[g] + acc * (1.f / 4096.f);
    }
    __syncthreads();

    // ---- fused gpre: 2 gate-columns per thread (512 cols total) ----
    int b = n >> 5, t = n & 31;               // Tt = 32
    float* Gdst = G + ((size_t)(t * Bb + b)) * 512;
#pragma unroll
    for (int rep = 0; rep < 2; ++rep) {
        int col = tid + rep * 256;
        int gg = col >> 7, u = col & 127;     // wave-uniform gg (64 | 128)
        const float* W    = (gg == 0) ? Wf : (gg == 1) ? Wi : (gg == 2) ? Wc : Wo;
        const float* bias = (gg == 0) ? bf : (gg == 1) ? bi : (gg == 2) ? bc : bo;
        float acc = bias[u];
#pragma unroll
        for (int k = 0; k < Ff; ++k) acc += feats[k] * W[k * Uu + u];
        Gdst[col] = acc;
    }
}

// ---------------------------------------------------------------------------
// Kernel 2: LSTM recurrence. One block per batch element, 1024 threads
// (16 waves -> exactly 4 waves/SIMD, hard 128-VGPR cap, pinned by
// __launch_bounds__(1024,4)).
// Weight residency: 32 named v2f SSA values + volatile keep-alive asm
// (executes once, outputs non-rematerializable). This round ALSO removes all
// per-step global traffic and its register overhead: the block's entire G
// slab (32x512 = 64 KB) is copied to LDS in the prologue, so the loop body
// touches only LDS + registers. Est. peak VGPR ~105 < 128 -> no spill.
// Thread (up = tid&63, g = (tid>>6)&3, q = tid>>8):
//   phase A: acc(v2f) = sum_{r<32} W_g[24+32q+r][2up..2up+1] * h[32q+r]
//            (h via broadcast ds_read_b64 + pk_fma op_sel splat)
//   phase B (tid<128): sum 4 chunk partials/gate + Gl[t], activations,
//            c/h update. 2 barriers per step.
// ---------------------------------------------------------------------------
__global__ __launch_bounds__(1024, 4) void lstm_kernel(
        const float* __restrict__ G,
        const float* __restrict__ Wf, const float* __restrict__ Wi,
        const float* __restrict__ Wc, const float* __restrict__ Wo,
        const float* __restrict__ out_w, const float* __restrict__ out_b,
        float* __restrict__ out) {
    int b   = blockIdx.x;
    int tid = threadIdx.x;
    int up  = tid & 63;                       // unit pair
    int g   = (tid >> 6) & 3;                 // gate (wave-uniform)
    int q   = tid >> 8;                       // row chunk (wave-uniform)
    const float* Wg = (g == 0) ? Wf : (g == 1) ? Wi : (g == 2) ? Wc : Wo;

    // 64 VGPRs of recurrent weights as named SSA values.
    const float* wbase = Wg + (size_t)(Ff + 32 * q) * Uu + 2 * up;
#define LDW(i) v2f w##i = *(const v2f*)(wbase + (size_t)(i) * Uu)
    LDW(0);  LDW(1);  LDW(2);  LDW(3);  LDW(4);  LDW(5);  LDW(6);  LDW(7);
    LDW(8);  LDW(9);  LDW(10); LDW(11); LDW(12); LDW(13); LDW(14); LDW(15);
    LDW(16); LDW(17); LDW(18); LDW(19); LDW(20); LDW(21); LDW(22); LDW(23);
    LDW(24); LDW(25); LDW(26); LDW(27); LDW(28); LDW(29); LDW(30); LDW(31);
#undef LDW
    // Volatile keep-alive: loads complete here, exactly once; outputs are the
    // loop-live values and cannot be rematerialized.
#define KA8(a,b_,c,d,e,f,g_,h) asm volatile("" : "+v"(a),"+v"(b_),"+v"(c),\
        "+v"(d),"+v"(e),"+v"(f),"+v"(g_),"+v"(h))
    KA8(w0,  w1,  w2,  w3,  w4,  w5,  w6,  w7);
    KA8(w8,  w9,  w10, w11, w12, w13, w14, w15);
    KA8(w16, w17, w18, w19, w20, w21, w22, w23);
    KA8(w24, w25, w26, w27, w28, w29, w30, w31);
#undef KA8

    __shared__ float Gl[Tt][512];             // 64 KB: this block's G slab
    __shared__ float hs[Uu];
    __shared__ float part[16][Uu];            // [q*4+g][u]
    __shared__ float hist[Tt][Uu];

    // Prologue: copy G[b] (32 steps x 512) to LDS, one coalesced 64 KB read.
    {
        int r  = tid >> 5;                    // 0..31 step
        int c0 = (tid & 31) * 16;             // 0..496
        const float4* src = (const float4*)(G + ((size_t)(r * Bb + b)) * 512 + c0);
        float4* dst = (float4*)(&Gl[r][c0]);
#pragma unroll
        for (int i = 0; i < 4; ++i) dst[i] = src[i];
    }

    float cs = 0.f;
    if (tid < Uu) hs[tid] = 0.f;
    __syncthreads();

    for (int t = 0; t < Tt; ++t) {
        // phase A: 16 broadcast ds_read_b64 + 32 pk_fma (2 indep chains).
        v2f ae = {0.f, 0.f}, ao = {0.f, 0.f};
        const v2f* hp = (const v2f*)(hs + q * 32);
        // even row 2j: splat h2.lo (op_sel_hi[1]=0); odd row: splat h2.hi.
#define FMA2(j, we, wo_) { v2f h2 = hp[j]; \
        asm("v_pk_fma_f32 %0, %1, %2, %0 op_sel:[0,0,0] op_sel_hi:[1,0,1]" \
            : "+v"(ae) : "v"(we), "v"(h2)); \
        asm("v_pk_fma_f32 %0, %1, %2, %0 op_sel:[0,1,0] op_sel_hi:[1,1,1]" \
            : "+v"(ao) : "v"(wo_), "v"(h2)); }
        FMA2(0,  w0,  w1);  FMA2(1,  w2,  w3);
        FMA2(2,  w4,  w5);  FMA2(3,  w6,  w7);
        FMA2(4,  w8,  w9);  FMA2(5,  w10, w11);
        FMA2(6,  w12, w13); FMA2(7,  w14, w15);
        FMA2(8,  w16, w17); FMA2(9,  w18, w19);
        FMA2(10, w20, w21); FMA2(11, w22, w23);
        FMA2(12, w24, w25); FMA2(13, w26, w27);
        FMA2(14, w28, w29); FMA2(15, w30, w31);
#undef FMA2
        v2f acc = ae + ao;
        *(v2f*)&part[q * 4 + g][2 * up] = acc;
        __syncthreads();

        // phase B: state update on 128 threads (G from LDS, zero global ops).
        if (tid < Uu) {
            int u = tid;
            float sf = part[0][u] + part[4][u] + part[8][u]  + part[12][u] + Gl[t][u];
            float si = part[1][u] + part[5][u] + part[9][u]  + part[13][u] + Gl[t][128 + u];
            float sg = part[2][u] + part[6][u] + part[10][u] + part[14][u] + Gl[t][256 + u];
            float so = part[3][u] + part[7][u] + part[11][u] + part[15][u] + Gl[t][384 + u];
            float f  = fast_sigmoid(sf);
            float i  = fast_sigmoid(si);
            float gg = fast_tanh(sg);
            float o  = fast_sigmoid(so);
            cs = cs * f + i * gg;
            float hn = fast_tanh(cs) * o;
            hs[u] = hn;
            hist[t][u] = hn;
        }
        __syncthreads();
    }

    // Epilogue: out[b][t] = hist[t] . out_w + out_b, 32 threads per t.
    int tt = tid >> 5, j = tid & 31;
    const float4* hh = (const float4*)(&hist[tt][j * 4]);
    float4 a0 = hh[0];
    const float* owp = out_w + j * 4;
    float pw = a0.x * owp[0] + a0.y * owp[1] + a0.z * owp[2] + a0.w * owp[3];
#pragma unroll
    for (int off = 16; off > 0; off >>= 1) pw += __shfl_down(pw, off, 32);
    if (j == 0) out[b * Tt + tt] = pw + out_b[0];
}

// ---------------------------------------------------------------------------
extern "C" void kernel_launch(void* const* d_in, const int* in_sizes, int n_in,
                              void* d_out, int out_size, void* d_ws, size_t ws_size,
                              hipStream_t stream) {
    const float* x   = (const float*)d_in[0];
    const float* w1  = (const float*)d_in[1];
    const float* b1  = (const float*)d_in[2];
    const float* w2  = (const float*)d_in[3];
    const float* b2  = (const float*)d_in[4];
    const float* Wf  = (const float*)d_in[5];
    const float* bf  = (const float*)d_in[6];
    const float* Wi  = (const float*)d_in[7];
    const float* bi  = (const float*)d_in[8];
    const float* Wc  = (const float*)d_in[9];
    const float* bc  = (const float*)d_in[10];
    const float* Wo  = (const float*)d_in[11];
    const float* bo  = (const float*)d_in[12];
    const float* ow  = (const float*)d_in[13];
    const float* ob  = (const float*)d_in[14];
    float* out = (float*)d_out;

    float* G = (float*)d_ws;                  // 256*512 = 131072 floats

    convfeat_kernel<<<Bb * Tt, 256, 0, stream>>>(x, w1, b1, w2, b2,
                                                 Wf, bf, Wi, bi, Wc, bc, Wo, bo, G);
    lstm_kernel<<<Bb, 1024, 0, stream>>>(G, Wf, Wi, Wc, Wo, ow, ob, out);
}

// Round 8
// 38.565 us; speedup vs baseline: 1.1828x; 1.0283x over previous
//
#include <hip/hip_runtime.h>
#include <math.h>

// Sizes (fixed by the problem)
#define Bb 8
#define Tt 32
#define Hh 64
#define Ww 64
#define Cc 3
#define Ff 24
#define Uu 128

typedef float v2f __attribute__((ext_vector_type(2)));

// Fast activations: |err| ~1e-6, threshold is 1.86e-4.
__device__ __forceinline__ float fast_sigmoid(float x) {
    float e = __builtin_amdgcn_exp2f(-1.442695040888963f * x);
    return __builtin_amdgcn_rcpf(1.f + e);
}
__device__ __forceinline__ float fast_tanh(float x) {
    float e = __builtin_amdgcn_exp2f(-2.885390081777927f * x);
    return 2.f * __builtin_amdgcn_rcpf(1.f + e) - 1.f;
}

// ---------------------------------------------------------------------------
// Kernel 1: fused per-frame stats + analytic double-conv + global-avg-pool
// + input-part of gate preactivations (feat never hits HBM).
// ---------------------------------------------------------------------------
__global__ void convfeat_kernel(const float* __restrict__ x,
                                const float* __restrict__ w1, const float* __restrict__ b1,
                                const float* __restrict__ w2, const float* __restrict__ b2,
                                const float* __restrict__ Wf, const float* __restrict__ bf,
                                const float* __restrict__ Wi, const float* __restrict__ bi,
                                const float* __restrict__ Wc, const float* __restrict__ bc,
                                const float* __restrict__ Wo, const float* __restrict__ bo,
                                float* __restrict__ G) {
    int n = blockIdx.x;                       // frame = b*T + t
    const float* xf = x + (size_t)n * (Hh * Ww * Cc);
    int tid  = threadIdx.x;                   // 0..255
    int row  = tid >> 2;
    int part = tid & 3;

    __shared__ float partial[256][3];
    __shared__ float rowsum[64][3];
    __shared__ float colv[64][12];
    __shared__ float st[75];                  // [c*25 + j]
    __shared__ float yst[24][9];
    __shared__ float feats[24];

    float s0 = 0.f, s1 = 0.f, s2 = 0.f;
    const float4* p4 = (const float4*)(xf + (row * Ww + part * 16) * Cc);
#pragma unroll
    for (int i = 0; i < 12; ++i) {
        float4 v = p4[i];
        int j = i * 4;
        float vv[4] = {v.x, v.y, v.z, v.w};
#pragma unroll
        for (int l = 0; l < 4; ++l) {
            int c = (j + l) % 3;
            if (c == 0) s0 += vv[l]; else if (c == 1) s1 += vv[l]; else s2 += vv[l];
        }
    }
    partial[tid][0] = s0; partial[tid][1] = s1; partial[tid][2] = s2;

    if (tid < 64) {
        int r = tid;
#pragma unroll
        for (int w4 = 0; w4 < 4; ++w4) {
            int w = (w4 < 2) ? w4 : 60 + w4;
#pragma unroll
            for (int c = 0; c < 3; ++c) colv[r][w4 * 3 + c] = xf[(r * Ww + w) * Cc + c];
        }
    }
    __syncthreads();

    if (part == 0) {
#pragma unroll
        for (int c = 0; c < 3; ++c)
            rowsum[row][c] = partial[tid][c] + partial[tid + 1][c]
                           + partial[tid + 2][c] + partial[tid + 3][c];
    }
    __syncthreads();

    if (tid < 3) {
        float t = 0.f;
        for (int r = 0; r < 64; ++r) t += rowsum[r][tid];
        st[tid * 25 + 0] = t;
    }
    if (tid >= 4 && tid < 16) {
        int k = tid - 4; int ri = k / 3, c = k % 3;
        int r = (ri < 2) ? ri : 60 + ri;
        st[c * 25 + 1 + ri] = rowsum[r][c];
    }
    if (tid >= 64 && tid < 76) {
        int k = tid - 64;
        float t = 0.f;
        for (int r = 0; r < 64; ++r) t += colv[r][k];
        int wi = k / 3, c = k % 3;
        st[c * 25 + 5 + wi] = t;
    }
    if (tid >= 128 && tid < 176) {
        int k = tid - 128; int pos = k / 3, c = k % 3;
        int ri = pos >> 2, wi = pos & 3;
        int r = (ri < 2) ? ri : 60 + ri;
        int w = (wi < 2) ? wi : 60 + wi;
        st[c * 25 + 9 + pos] = xf[(r * Ww + w) * Cc + c];
    }
    __syncthreads();

    if (tid < 24) {
        int f = tid;
        float Sy = 0, r0 = 0, r63 = 0, c0 = 0, c63 = 0, y00 = 0, y0W = 0, yH0 = 0, yHW = 0;
        for (int c = 0; c < 3; ++c) {
            const float* S = st + c * 25;
            float Sx = S[0];
            float rX[4] = {S[1], S[2], S[3], S[4]};
            float cX[4] = {S[5], S[6], S[7], S[8]};
            const float* X = S + 9;
            #define W1(p, q) w1[(((p) * 3 + (q)) * 3 + c) * 24 + f]
#pragma unroll
            for (int p = 0; p < 3; ++p)
#pragma unroll
                for (int q = 0; q < 3; ++q) {
                    float t = Sx;
                    if (p == 0) t -= rX[3];
                    if (p == 2) t -= rX[0];
                    if (q == 0) t -= cX[3];
                    if (q == 2) t -= cX[0];
                    if (p == 0 && q == 0) t += X[3 * 4 + 3];
                    if (p == 0 && q == 2) t += X[3 * 4 + 0];
                    if (p == 2 && q == 0) t += X[0 * 4 + 3];
                    if (p == 2 && q == 2) t += X[0 * 4 + 0];
                    Sy += W1(p, q) * t;
                }
#pragma unroll
            for (int q = 0; q < 3; ++q) {
                float Rr0  = rX[0] - ((q == 0) ? X[0 * 4 + 3] : 0.f) - ((q == 2) ? X[0 * 4 + 0] : 0.f);
                float Rr1  = rX[1] - ((q == 0) ? X[1 * 4 + 3] : 0.f) - ((q == 2) ? X[1 * 4 + 0] : 0.f);
                float Rr62 = rX[2] - ((q == 0) ? X[2 * 4 + 3] : 0.f) - ((q == 2) ? X[2 * 4 + 0] : 0.f);
                float Rr63 = rX[3] - ((q == 0) ? X[3 * 4 + 3] : 0.f) - ((q == 2) ? X[3 * 4 + 0] : 0.f);
                r0  += W1(1, q) * Rr0  + W1(2, q) * Rr1;
                r63 += W1(0, q) * Rr62 + W1(1, q) * Rr63;
            }
#pragma unroll
            for (int p = 0; p < 3; ++p) {
                float Rc0  = cX[0] - ((p == 0) ? X[3 * 4 + 0] : 0.f) - ((p == 2) ? X[0 * 4 + 0] : 0.f);
                float Rc1  = cX[1] - ((p == 0) ? X[3 * 4 + 1] : 0.f) - ((p == 2) ? X[0 * 4 + 1] : 0.f);
                float Rc62 = cX[2] - ((p == 0) ? X[3 * 4 + 2] : 0.f) - ((p == 2) ? X[0 * 4 + 2] : 0.f);
                float Rc63 = cX[3] - ((p == 0) ? X[3 * 4 + 3] : 0.f) - ((p == 2) ? X[0 * 4 + 3] : 0.f);
                c0  += W1(p, 1) * Rc0  + W1(p, 2) * Rc1;
                c63 += W1(p, 0) * Rc62 + W1(p, 1) * Rc63;
            }
            y00 += W1(1, 1) * X[0 * 4 + 0] + W1(1, 2) * X[0 * 4 + 1]
                 + W1(2, 1) * X[1 * 4 + 0] + W1(2, 2) * X[1 * 4 + 1];
            y0W += W1(1, 0) * X[0 * 4 + 2] + W1(1, 1) * X[0 * 4 + 3]
                 + W1(2, 0) * X[1 * 4 + 2] + W1(2, 1) * X[1 * 4 + 3];
            yH0 += W1(0, 1) * X[2 * 4 + 0] + W1(0, 2) * X[2 * 4 + 1]
                 + W1(1, 1) * X[3 * 4 + 0] + W1(1, 2) * X[3 * 4 + 1];
            yHW += W1(0, 0) * X[2 * 4 + 2] + W1(0, 1) * X[2 * 4 + 3]
                 + W1(1, 0) * X[3 * 4 + 2] + W1(1, 1) * X[3 * 4 + 3];
            #undef W1
        }
        float bb = b1[f];
        yst[f][0] = Sy + 4096.f * bb;
        yst[f][1] = r0 + 64.f * bb;
        yst[f][2] = r63 + 64.f * bb;
        yst[f][3] = c0 + 64.f * bb;
        yst[f][4] = c63 + 64.f * bb;
        yst[f][5] = y00 + bb; yst[f][6] = y0W + bb;
        yst[f][7] = yH0 + bb; yst[f][8] = yHW + bb;
    }
    __syncthreads();

    if (tid < 24) {
        int g = tid;
        float acc = 0.f;
        for (int f = 0; f < 24; ++f) {
            float Sy = yst[f][0], rY0 = yst[f][1], rY63 = yst[f][2], cY0 = yst[f][3], cY63 = yst[f][4];
            float yc00 = yst[f][5], yc0W = yst[f][6], ycH0 = yst[f][7], ycHW = yst[f][8];
#pragma unroll
            for (int p = 0; p < 3; ++p)
#pragma unroll
                for (int q = 0; q < 3; ++q) {
                    float t = Sy;
                    if (p == 0) t -= rY63;
                    if (p == 2) t -= rY0;
                    if (q == 0) t -= cY63;
                    if (q == 2) t -= cY0;
                    if (p == 0 && q == 0) t += ycHW;
                    if (p == 0 && q == 2) t += ycH0;
                    if (p == 2 && q == 0) t += yc0W;
                    if (p == 2 && q == 2) t += yc00;
                    acc += w2[(((p * 3 + q) * 24 + f) * 24) + g] * t;
                }
        }
        feats[g] = b2[g] + acc * (1.f / 4096.f);
    }
    __syncthreads();

    // ---- fused gpre: 2 gate-columns per thread (512 cols total) ----
    int b = n >> 5, t = n & 31;               // Tt = 32
    float* Gdst = G + ((size_t)(t * Bb + b)) * 512;
#pragma unroll
    for (int rep = 0; rep < 2; ++rep) {
        int col = tid + rep * 256;
        int gg = col >> 7, u = col & 127;     // wave-uniform gg (64 | 128)
        const float* W    = (gg == 0) ? Wf : (gg == 1) ? Wi : (gg == 2) ? Wc : Wo;
        const float* bias = (gg == 0) ? bf : (gg == 1) ? bi : (gg == 2) ? bc : bo;
        float acc = bias[u];
#pragma unroll
        for (int k = 0; k < Ff; ++k) acc += feats[k] * W[k * Uu + u];
        Gdst[col] = acc;
    }
}

// ---------------------------------------------------------------------------
// Kernel 2: LSTM recurrence. One block per batch element, 512 threads
// (8 waves, 2 waves/SIMD, 256-VGPR cap via __launch_bounds__(512,2)).
// DS-throughput redesign (round 7 was LDS-pipe bound at ~272 DS instr/step):
// thread = (q = tid>>7: 32-row chunk) x (cg = tid&127: 4 output columns).
// Weights: 32 rows x 4 cols = 128 VGPRs as 64 NAMED v2f SSA values +
// volatile keep-alive (arrays provably go to scratch; sinking provably
// happens without the keep-alive).
// Per step per wave: 8 ds_read_b128 (h chunk) + 64 pk_fma + 1 ds_write_b128
// -> 9 DS instrs/wave (vs 17), 8 waves (vs 16): ~116 DS instrs/step total.
// phase B (tid<128): sum 4 chunk-partials/gate + Gl[t], activations, c/h.
// 2 barriers per step.
// ---------------------------------------------------------------------------
__global__ __launch_bounds__(512, 2) void lstm_kernel(
        const float* __restrict__ G,
        const float* __restrict__ Wf, const float* __restrict__ Wi,
        const float* __restrict__ Wc, const float* __restrict__ Wo,
        const float* __restrict__ out_w, const float* __restrict__ out_b,
        float* __restrict__ out) {
    int b   = blockIdx.x;
    int tid = threadIdx.x;
    int cg  = tid & 127;                      // column group (4 cols)
    int q   = tid >> 7;                       // row chunk (wave-uniform)
    int gate = cg >> 5;                       // wave-... varies per half-wave? no: cg 0..127 within wave pair; gate varies within wave but branch below is resolved per-thread via pointer select (uniform cost).
    int c0   = (cg & 31) * 4;                 // column offset within gate
    const float* Wg = (gate == 0) ? Wf : (gate == 1) ? Wi : (gate == 2) ? Wc : Wo;

    // 128 VGPRs of recurrent weights as 64 named v2f SSA values.
    // Row r covers cols (c0, c0+1) in a##r and (c0+2, c0+3) in b##r.
    const float* wbase = Wg + (size_t)(Ff + 32 * q) * Uu + c0;
#define LDW(i) v2f a##i = *(const v2f*)(wbase + (size_t)(i) * Uu); \
               v2f b##i = *(const v2f*)(wbase + (size_t)(i) * Uu + 2)
    LDW(0);  LDW(1);  LDW(2);  LDW(3);  LDW(4);  LDW(5);  LDW(6);  LDW(7);
    LDW(8);  LDW(9);  LDW(10); LDW(11); LDW(12); LDW(13); LDW(14); LDW(15);
    LDW(16); LDW(17); LDW(18); LDW(19); LDW(20); LDW(21); LDW(22); LDW(23);
    LDW(24); LDW(25); LDW(26); LDW(27); LDW(28); LDW(29); LDW(30); LDW(31);
#undef LDW
    // Volatile keep-alive: loads complete here exactly once; outputs are the
    // loop-live values and cannot be rematerialized or sunk into the loop.
#define KA8(p0,p1,p2,p3,p4,p5,p6,p7) asm volatile("" : "+v"(p0),"+v"(p1),\
        "+v"(p2),"+v"(p3),"+v"(p4),"+v"(p5),"+v"(p6),"+v"(p7))
    KA8(a0,b0,a1,b1,a2,b2,a3,b3);       KA8(a4,b4,a5,b5,a6,b6,a7,b7);
    KA8(a8,b8,a9,b9,a10,b10,a11,b11);   KA8(a12,b12,a13,b13,a14,b14,a15,b15);
    KA8(a16,b16,a17,b17,a18,b18,a19,b19); KA8(a20,b20,a21,b21,a22,b22,a23,b23);
    KA8(a24,b24,a25,b25,a26,b26,a27,b27); KA8(a28,b28,a29,b29,a30,b30,a31,b31);
#undef KA8

    __shared__ float Gl[Tt][512];             // 64 KB: this block's G slab
    __shared__ __align__(16) float hs[Uu];
    __shared__ float part[4][512];            // [q][gate*128 + u]
    __shared__ float hist[Tt][Uu];

    // Prologue: copy G[b] (32 steps x 512) to LDS, coalesced (32 f/thread).
    {
        int r  = tid >> 4;                    // 0..31 step
        int cc = (tid & 15) * 32;             // 0..480
        const float4* src = (const float4*)(G + ((size_t)(r * Bb + b)) * 512 + cc);
        float4* dst = (float4*)(&Gl[r][cc]);
#pragma unroll
        for (int i = 0; i < 8; ++i) dst[i] = src[i];
    }

    float cs = 0.f;
    if (tid < Uu) hs[tid] = 0.f;
    __syncthreads();

    for (int t = 0; t < Tt; ++t) {
        // phase A: 8 ds_read_b128 + 64 pk_fma on 4 independent chains.
        v2f ae0 = {0.f, 0.f}, ao0 = {0.f, 0.f};  // col pair (c0, c0+1)
        v2f ae1 = {0.f, 0.f}, ao1 = {0.f, 0.f};  // col pair (c0+2, c0+3)
        const float4* hp = (const float4*)(hs + q * 32);
        // FMA4: rows 4j..4j+3 with h quad hq. lo-splat = op_sel_hi[1]=0 on
        // the v2f pair; hi-splat = op_sel[1]=1 (numerically proven r2-r7).
#define FMA4(hq, wA0,wB0, wA1,wB1, wA2,wB2, wA3,wB3) { \
        v2f hlo = {hq.x, hq.y}; v2f hhi = {hq.z, hq.w}; \
        asm("v_pk_fma_f32 %0, %1, %2, %0 op_sel:[0,0,0] op_sel_hi:[1,0,1]" \
            : "+v"(ae0) : "v"(wA0), "v"(hlo)); \
        asm("v_pk_fma_f32 %0, %1, %2, %0 op_sel:[0,0,0] op_sel_hi:[1,0,1]" \
            : "+v"(ae1) : "v"(wB0), "v"(hlo)); \
        asm("v_pk_fma_f32 %0, %1, %2, %0 op_sel:[0,1,0] op_sel_hi:[1,1,1]" \
            : "+v"(ao0) : "v"(wA1), "v"(hlo)); \
        asm("v_pk_fma_f32 %0, %1, %2, %0 op_sel:[0,1,0] op_sel_hi:[1,1,1]" \
            : "+v"(ao1) : "v"(wB1), "v"(hlo)); \
        asm("v_pk_fma_f32 %0, %1, %2, %0 op_sel:[0,0,0] op_sel_hi:[1,0,1]" \
            : "+v"(ae0) : "v"(wA2), "v"(hhi)); \
        asm("v_pk_fma_f32 %0, %1, %2, %0 op_sel:[0,0,0] op_sel_hi:[1,0,1]" \
            : "+v"(ae1) : "v"(wB2), "v"(hhi)); \
        asm("v_pk_fma_f32 %0, %1, %2, %0 op_sel:[0,1,0] op_sel_hi:[1,1,1]" \
            : "+v"(ao0) : "v"(wA3), "v"(hhi)); \
        asm("v_pk_fma_f32 %0, %1, %2, %0 op_sel:[0,1,0] op_sel_hi:[1,1,1]" \
            : "+v"(ao1) : "v"(wB3), "v"(hhi)); }
        { float4 h0 = hp[0]; FMA4(h0, a0,b0, a1,b1, a2,b2, a3,b3); }
        { float4 h1 = hp[1]; FMA4(h1, a4,b4, a5,b5, a6,b6, a7,b7); }
        { float4 h2 = hp[2]; FMA4(h2, a8,b8, a9,b9, a10,b10, a11,b11); }
        { float4 h3 = hp[3]; FMA4(h3, a12,b12, a13,b13, a14,b14, a15,b15); }
        { float4 h4 = hp[4]; FMA4(h4, a16,b16, a17,b17, a18,b18, a19,b19); }
        { float4 h5 = hp[5]; FMA4(h5, a20,b20, a21,b21, a22,b22, a23,b23); }
        { float4 h6 = hp[6]; FMA4(h6, a24,b24, a25,b25, a26,b26, a27,b27); }
        { float4 h7 = hp[7]; FMA4(h7, a28,b28, a29,b29, a30,b30, a31,b31); }
#undef FMA4
        v2f s0 = ae0 + ao0, s1 = ae1 + ao1;
        float4 pw4; pw4.x = s0.x; pw4.y = s0.y; pw4.z = s1.x; pw4.w = s1.y;
        *(float4*)&part[q][gate * 128 + c0] = pw4;
        __syncthreads();

        // phase B: state update on 128 threads (all data from LDS).
        if (tid < Uu) {
            int u = tid;
            float sf = part[0][u]       + part[1][u]       + part[2][u]       + part[3][u]       + Gl[t][u];
            float si = part[0][128 + u] + part[1][128 + u] + part[2][128 + u] + part[3][128 + u] + Gl[t][128 + u];
            float sg = part[0][256 + u] + part[1][256 + u] + part[2][256 + u] + part[3][256 + u] + Gl[t][256 + u];
            float so = part[0][384 + u] + part[1][384 + u] + part[2][384 + u] + part[3][384 + u] + Gl[t][384 + u];
            float f  = fast_sigmoid(sf);
            float i  = fast_sigmoid(si);
            float gg = fast_tanh(sg);
            float o  = fast_sigmoid(so);
            cs = cs * f + i * gg;
            float hn = fast_tanh(cs) * o;
            hs[u] = hn;
            hist[t][u] = hn;
        }
        __syncthreads();
    }

    // Epilogue: out[b][t] = hist[t] . out_w + out_b, 16 threads per t.
    int tt = tid >> 4, j = tid & 15;
    const float4* hh = (const float4*)(&hist[tt][j * 8]);
    float4 a0q = hh[0], a1q = hh[1];
    const float* owp = out_w + j * 8;
    float pw = a0q.x * owp[0] + a0q.y * owp[1] + a0q.z * owp[2] + a0q.w * owp[3]
             + a1q.x * owp[4] + a1q.y * owp[5] + a1q.z * owp[6] + a1q.w * owp[7];
#pragma unroll
    for (int off = 8; off > 0; off >>= 1) pw += __shfl_down(pw, off, 16);
    if (j == 0) out[b * Tt + tt] = pw + out_b[0];
}

// ---------------------------------------------------------------------------
extern "C" void kernel_launch(void* const* d_in, const int* in_sizes, int n_in,
                              void* d_out, int out_size, void* d_ws, size_t ws_size,
                              hipStream_t stream) {
    const float* x   = (const float*)d_in[0];
    const float* w1  = (const float*)d_in[1];
    const float* b1  = (const float*)d_in[2];
    const float* w2  = (const float*)d_in[3];
    const float* b2  = (const float*)d_in[4];
    const float* Wf  = (const float*)d_in[5];
    const float* bf  = (const float*)d_in[6];
    const float* Wi  = (const float*)d_in[7];
    const float* bi  = (const float*)d_in[8];
    const float* Wc  = (const float*)d_in[9];
    const float* bc  = (const float*)d_in[10];
    const float* Wo  = (const float*)d_in[11];
    const float* bo  = (const float*)d_in[12];
    const float* ow  = (const float*)d_in[13];
    const float* ob  = (const float*)d_in[14];
    float* out = (float*)d_out;

    float* G = (float*)d_ws;                  // 256*512 = 131072 floats

    convfeat_kernel<<<Bb * Tt, 256, 0, stream>>>(x, w1, b1, w2, b2,
                                                 Wf, bf, Wi, bi, Wc, bc, Wo, bo, G);
    lstm_kernel<<<Bb, 512, 0, stream>>>(G, Wf, Wi, Wc, Wo, ow, ob, out);
}